// Round 1
// baseline (338.655 us; speedup 1.0000x reference)
//
#include <hip/hip_runtime.h>
#include <cmath>

#define NRAYS 4096

// Transposed workspace layout (all float):
//   dp_t[i][y][x][c16], ap_t[i][y][x][c24], dl_t[i][l][c16], al_t[i][l][c24]
static constexpr int APT_OFS = 3 * 256 * 256 * 16;            // 3145728
static constexpr int DLT_OFS = APT_OFS + 3 * 256 * 256 * 24;  // 7864320
static constexpr int ALT_OFS = DLT_OFS + 3 * 256 * 16;        // 7876608
static constexpr int WS_FLOATS = ALT_OFS + 3 * 256 * 24;      // 7895040

__global__ __launch_bounds__(256) void transpose_kernel(
    const float* __restrict__ dp, const float* __restrict__ dl,
    const float* __restrict__ ap, const float* __restrict__ al,
    float* __restrict__ ws) {
  int idx = blockIdx.x * blockDim.x + threadIdx.x;
  int stride = gridDim.x * blockDim.x;
  for (; idx < WS_FLOATS; idx += stride) {
    if (idx < APT_OFS) {
      int t = idx;
      int c = t & 15; t >>= 4;
      int x = t & 255; t >>= 8;
      int y = t & 255; t >>= 8;                       // t = i
      ws[idx] = dp[((t * 16 + c) * 256 + y) * 256 + x];
    } else if (idx < DLT_OFS) {
      int t = idx - APT_OFS;
      int c = t % 24; t /= 24;
      int x = t & 255; t >>= 8;
      int y = t & 255; t >>= 8;                       // t = i
      ws[idx] = ap[((t * 24 + c) * 256 + y) * 256 + x];
    } else if (idx < ALT_OFS) {
      int t = idx - DLT_OFS;
      int c = t & 15; t >>= 4;
      int l = t & 255; t >>= 8;                       // t = i
      ws[idx] = dl[(t * 16 + c) * 256 + l];
    } else {
      int t = idx - ALT_OFS;
      int c = t % 24; t /= 24;
      int l = t & 255; t >>= 8;                       // t = i
      ws[idx] = al[(t * 24 + c) * 256 + l];
    }
  }
}

__device__ __forceinline__ float4 ld4(const float* p) { return *(const float4*)p; }

__device__ __forceinline__ float4 lerp4(float4 a, float4 b, float w) {
  float4 o;
  o.x = fmaf(w, b.x - a.x, a.x);
  o.y = fmaf(w, b.y - a.y, a.y);
  o.z = fmaf(w, b.z - a.z, a.z);
  o.w = fmaf(w, b.w - a.w, a.w);
  return o;
}

// align_corners=True grid coord -> (i0, frac). N=256 fixed.
__device__ __forceinline__ void grid_uv(float c, int& i0, float& w) {
  float f = (c + 1.0f) * 127.5f;
  float fl = floorf(f);
  fl = fminf(fmaxf(fl, 0.0f), 254.0f);
  i0 = (int)fl;
  w = f - fl;
}

// ---- density mode sampler: sum over 16ch of bilinear(plane)*lin(line) ----
template <bool TR>
__device__ __forceinline__ float density_mode(const float* __restrict__ plane,
                                              const float* __restrict__ line,
                                              float cx, float cy, float cw) {
  int x0, y0, l0; float wx, wy, wl;
  grid_uv(cx, x0, wx);
  grid_uv(cy, y0, wy);
  grid_uv(cw, l0, wl);
  float s = 0.0f;
  if constexpr (TR) {
    const float* p00 = plane + (y0 * 256 + x0) * 16;
    const float* p10 = p00 + 256 * 16;
    const float* lp = line + l0 * 16;
#pragma unroll
    for (int cc = 0; cc < 4; ++cc) {
      float4 v00 = ld4(p00 + cc * 4);
      float4 v01 = ld4(p00 + 16 + cc * 4);
      float4 v10 = ld4(p10 + cc * 4);
      float4 v11 = ld4(p10 + 16 + cc * 4);
      float4 top = lerp4(v00, v01, wx);
      float4 bot = lerp4(v10, v11, wx);
      float4 mid = lerp4(top, bot, wy);
      float4 la = ld4(lp + cc * 4);
      float4 lb = ld4(lp + 16 + cc * 4);
      float4 lv = lerp4(la, lb, wl);
      s += mid.x * lv.x + mid.y * lv.y + mid.z * lv.z + mid.w * lv.w;
    }
  } else {
    int base = y0 * 256 + x0;
#pragma unroll 4
    for (int c = 0; c < 16; ++c) {
      const float* pc = plane + c * 65536;
      float v00 = pc[base], v01 = pc[base + 1];
      float v10 = pc[base + 256], v11 = pc[base + 257];
      float top = fmaf(wx, v01 - v00, v00);
      float bot = fmaf(wx, v11 - v10, v10);
      float mid = fmaf(wy, bot - top, top);
      float la = line[c * 256 + l0], lb = line[c * 256 + l0 + 1];
      float lv = fmaf(wl, lb - la, la);
      s += mid * lv;
    }
  }
  return s;
}

// ---- app mode sampler: accumulate 3 basis dot products over 24ch ----
template <bool TR>
__device__ __forceinline__ void app_mode(const float* __restrict__ plane,
                                         const float* __restrict__ line,
                                         const float* __restrict__ btR,
                                         const float* __restrict__ btG,
                                         const float* __restrict__ btB,
                                         float cx, float cy, float cw,
                                         float& dr, float& dg, float& db) {
  int x0, y0, l0; float wx, wy, wl;
  grid_uv(cx, x0, wx);
  grid_uv(cy, y0, wy);
  grid_uv(cw, l0, wl);
  if constexpr (TR) {
    const float* p00 = plane + (y0 * 256 + x0) * 24;
    const float* p10 = p00 + 256 * 24;
    const float* lp = line + l0 * 24;
#pragma unroll
    for (int cc = 0; cc < 6; ++cc) {
      float4 v00 = ld4(p00 + cc * 4);
      float4 v01 = ld4(p00 + 24 + cc * 4);
      float4 v10 = ld4(p10 + cc * 4);
      float4 v11 = ld4(p10 + 24 + cc * 4);
      float4 top = lerp4(v00, v01, wx);
      float4 bot = lerp4(v10, v11, wx);
      float4 mid = lerp4(top, bot, wy);
      float4 la = ld4(lp + cc * 4);
      float4 lb = ld4(lp + 24 + cc * 4);
      float4 lv = lerp4(la, lb, wl);
      float4 av;
      av.x = mid.x * lv.x; av.y = mid.y * lv.y;
      av.z = mid.z * lv.z; av.w = mid.w * lv.w;
      float4 br = ld4(btR + cc * 4);
      float4 bg = ld4(btG + cc * 4);
      float4 bbv = ld4(btB + cc * 4);
      dr += av.x * br.x + av.y * br.y + av.z * br.z + av.w * br.w;
      dg += av.x * bg.x + av.y * bg.y + av.z * bg.z + av.w * bg.w;
      db += av.x * bbv.x + av.y * bbv.y + av.z * bbv.z + av.w * bbv.w;
    }
  } else {
    int base = y0 * 256 + x0;
#pragma unroll 4
    for (int c = 0; c < 24; ++c) {
      const float* pc = plane + c * 65536;
      float v00 = pc[base], v01 = pc[base + 1];
      float v10 = pc[base + 256], v11 = pc[base + 257];
      float top = fmaf(wx, v01 - v00, v00);
      float bot = fmaf(wx, v11 - v10, v10);
      float mid = fmaf(wy, bot - top, top);
      float la = line[c * 256 + l0], lb = line[c * 256 + l0 + 1];
      float lv = fmaf(wl, lb - la, la);
      float av = mid * lv;
      dr += av * btR[c];
      dg += av * btG[c];
      db += av * btB[c];
    }
  }
}

// One wave (64 lanes) per ray; sample j = q*64 + lane (adjacent lanes are
// adjacent samples -> coherent gathers). Transmittance cumprod via shuffle
// product-scan per 64-sample chunk + running scalar carry.
template <bool TR>
__global__ __launch_bounds__(256) void render_kernel(
    const float* __restrict__ rays, const float* __restrict__ basis,
    const float* __restrict__ aabb, const float* __restrict__ dplane,
    const float* __restrict__ dline, const float* __restrict__ aplane,
    const float* __restrict__ aline, float* __restrict__ out) {
  __shared__ __align__(16) float bt[3 * 72];  // bt[k][r] = basis[r][k]
  int tid = threadIdx.x;
  if (tid < 216) {
    int k = tid / 72, r = tid - k * 72;
    bt[tid] = basis[r * 3 + k];
  }
  __syncthreads();

  int lane = tid & 63;
  int ray = blockIdx.x * 4 + (tid >> 6);

  float o0 = rays[ray * 6 + 0], o1 = rays[ray * 6 + 1], o2 = rays[ray * 6 + 2];
  float d0 = rays[ray * 6 + 3], d1 = rays[ray * 6 + 4], d2 = rays[ray * 6 + 5];
  float A0 = aabb[0], A1 = aabb[1], A2 = aabb[2];
  float B0 = aabb[3], B1 = aabb[4], B2 = aabb[5];

  float v0 = fabsf(d0) < 1e-6f ? 1e-6f : d0;
  float v1 = fabsf(d1) < 1e-6f ? 1e-6f : d1;
  float v2 = fabsf(d2) < 1e-6f ? 1e-6f : d2;
  float ra0 = (B0 - o0) / v0, rb0 = (A0 - o0) / v0;
  float ra1 = (B1 - o1) / v1, rb1 = (A1 - o1) / v1;
  float ra2 = (B2 - o2) / v2, rb2 = (A2 - o2) / v2;
  float tmin = fmaxf(fmaxf(fminf(ra0, rb0), fminf(ra1, rb1)), fminf(ra2, rb2));
  tmin = fmaxf(tmin, 0.05f);
  float tmax = fminf(fminf(fmaxf(ra0, rb0), fmaxf(ra1, rb1)), fmaxf(ra2, rb2));
  tmax = fmaxf(tmax, tmin + 0.001f);
  float dt = (tmax - tmin) * (1.0f / 255.0f);

  float s0 = 2.0f / (B0 - A0), s1 = 2.0f / (B1 - A1), s2 = 2.0f / (B2 - A2);

  float C = 1.0f;  // transmittance entering current 64-sample chunk
  float racc = 0.f, gacc = 0.f, bacc = 0.f, wsum = 0.f, dsum = 0.f;

  for (int q = 0; q < 4; ++q) {
    int j = q * 64 + lane;
    float sfrac = (float)j * (1.0f / 255.0f);
    float z = tmin * (1.0f - sfrac) + tmax * sfrac;
    float c0 = (o0 + d0 * z - A0) * s0 - 1.0f;
    float c1 = (o1 + d1 * z - A1) * s1 - 1.0f;
    float c2 = (o2 + d2 * z - A2) * s2 - 1.0f;
    bool inside = (fabsf(c0) <= 1.0f) && (fabsf(c1) <= 1.0f) && (fabsf(c2) <= 1.0f);
    float alpha = 0.f, cr = 0.f, cg = 0.f, cb = 0.f;
    if (inside) {
      float sig = 0.f, dr = 0.f, dg = 0.f, db = 0.f;
      // MAT_MODE = [(0,1),(0,2),(1,2)], VEC_MODE = [2,1,0]
      sig += density_mode<TR>(dplane + 0 * 1048576, dline + 0 * 4096, c0, c1, c2);
      sig += density_mode<TR>(dplane + 1 * 1048576, dline + 1 * 4096, c0, c2, c1);
      sig += density_mode<TR>(dplane + 2 * 1048576, dline + 2 * 4096, c1, c2, c0);
      app_mode<TR>(aplane + 0 * 1572864, aline + 0 * 6144,
                   &bt[0 * 72 + 0], &bt[1 * 72 + 0], &bt[2 * 72 + 0],
                   c0, c1, c2, dr, dg, db);
      app_mode<TR>(aplane + 1 * 1572864, aline + 1 * 6144,
                   &bt[0 * 72 + 24], &bt[1 * 72 + 24], &bt[2 * 72 + 24],
                   c0, c2, c1, dr, dg, db);
      app_mode<TR>(aplane + 2 * 1572864, aline + 2 * 6144,
                   &bt[0 * 72 + 48], &bt[1 * 72 + 48], &bt[2 * 72 + 48],
                   c1, c2, c0, dr, dg, db);
      // softplus (stable) -> alpha; sigmoid -> color
      float sp = fmaxf(sig, 0.f) + log1pf(expf(-fabsf(sig)));
      alpha = 1.0f - expf(-sp * dt);
      cr = 1.0f / (1.0f + expf(-dr));
      cg = 1.0f / (1.0f + expf(-dg));
      cb = 1.0f / (1.0f + expf(-db));
    }
    // product scan of m = 1 - alpha + 1e-10 across lanes
    float m = 1.0f - alpha + 1e-10f;
    float p = m;
#pragma unroll
    for (int off = 1; off < 64; off <<= 1) {
      float t = __shfl_up(p, off, 64);
      if (lane >= off) p *= t;
    }
    float tot = __shfl(p, 63, 64);     // full chunk product
    float e = __shfl_up(p, 1, 64);     // exclusive scan
    if (lane == 0) e = 1.0f;
    float Tj = C * e;
    float w = alpha * Tj;
    racc += w * cr; gacc += w * cg; bacc += w * cb;
    wsum += w; dsum += w * z;
    C *= tot;
  }

#pragma unroll
  for (int off = 32; off > 0; off >>= 1) {
    racc += __shfl_down(racc, off, 64);
    gacc += __shfl_down(gacc, off, 64);
    bacc += __shfl_down(bacc, off, 64);
    wsum += __shfl_down(wsum, off, 64);
    dsum += __shfl_down(dsum, off, 64);
  }
  if (lane == 0) {
    float bgw = 1.0f - wsum;  // WHITE_BG
    out[ray * 3 + 0] = fminf(fmaxf(racc + bgw, 0.f), 1.f);
    out[ray * 3 + 1] = fminf(fmaxf(gacc + bgw, 0.f), 1.f);
    out[ray * 3 + 2] = fminf(fmaxf(bacc + bgw, 0.f), 1.f);
    out[NRAYS * 3 + ray] = dsum;
  }
}

extern "C" void kernel_launch(void* const* d_in, const int* in_sizes, int n_in,
                              void* d_out, int out_size, void* d_ws, size_t ws_size,
                              hipStream_t stream) {
  const float* rays  = (const float*)d_in[0];
  const float* dp    = (const float*)d_in[1];
  const float* dl    = (const float*)d_in[2];
  const float* ap    = (const float*)d_in[3];
  const float* al    = (const float*)d_in[4];
  const float* basis = (const float*)d_in[5];
  const float* aabb  = (const float*)d_in[6];
  // d_in[7] = N_samples (=256, hardcoded in kernel structure)
  float* out = (float*)d_out;

  if (ws_size >= (size_t)WS_FLOATS * sizeof(float)) {
    float* ws = (float*)d_ws;
    transpose_kernel<<<2048, 256, 0, stream>>>(dp, dl, ap, al, ws);
    render_kernel<true><<<NRAYS / 4, 256, 0, stream>>>(
        rays, basis, aabb,
        ws, ws + DLT_OFS, ws + APT_OFS, ws + ALT_OFS, out);
  } else {
    // Workspace too small for transposed textures: sample original layout.
    render_kernel<false><<<NRAYS / 4, 256, 0, stream>>>(
        rays, basis, aabb, dp, dl, ap, al, out);
  }
}

// Round 2
// 267.784 us; speedup vs baseline: 1.2647x; 1.2647x over previous
//
#include <hip/hip_runtime.h>
#include <cmath>

#define NRAYS 4096
#define NSAMP 256
#define NSAMPLES_TOT (NRAYS * NSAMP)

// Transposed workspace layout (all float):
//   dp_t[i][y][x][c16], ap_t[i][y][x][c24], dl_t[i][l][c16], al_t[i][l][c24]
static constexpr int APT_OFS = 3 * 256 * 256 * 16;            // 3145728
static constexpr int DLT_OFS = APT_OFS + 3 * 256 * 256 * 24;  // 7864320
static constexpr int ALT_OFS = DLT_OFS + 3 * 256 * 16;        // 7876608
static constexpr int WS_FLOATS = ALT_OFS + 3 * 256 * 24;      // 7895040
static constexpr int SMP_OFS = WS_FLOATS;                     // float4-aligned
static constexpr size_t WS_NEED_FULL =
    ((size_t)WS_FLOATS + 4ull * NSAMPLES_TOT) * sizeof(float);  // ~48.4 MB

__device__ __forceinline__ float4 ld4(const float* p) { return *(const float4*)p; }

__device__ __forceinline__ float4 lerp4(float4 a, float4 b, float w) {
  float4 o;
  o.x = fmaf(w, b.x - a.x, a.x);
  o.y = fmaf(w, b.y - a.y, a.y);
  o.z = fmaf(w, b.z - a.z, a.z);
  o.w = fmaf(w, b.w - a.w, a.w);
  return o;
}

__device__ __forceinline__ float dot4(float4 a, float4 b) {
  return a.x * b.x + a.y * b.y + a.z * b.z + a.w * b.w;
}

// align_corners=True grid coord -> (i0, frac). N=256 fixed.
__device__ __forceinline__ void grid_uv(float c, int& i0, float& w) {
  float f = (c + 1.0f) * 127.5f;
  float fl = floorf(f);
  fl = fminf(fmaxf(fl, 0.0f), 254.0f);
  i0 = (int)fl;
  w = f - fl;
}

// ---------------------------------------------------------------------------
// Transpose: one output float4 per thread. Writes fully coalesced (16B/lane
// contiguous); reads share 64B lines across the 4 components / adjacent hw.
// ---------------------------------------------------------------------------
__global__ __launch_bounds__(256) void transpose4_kernel(
    const float* __restrict__ dp, const float* __restrict__ dl,
    const float* __restrict__ ap, const float* __restrict__ al,
    float4* __restrict__ ws4) {
  constexpr int DP4 = 3 * 65536 * 4;  // 786432
  constexpr int AP4 = 3 * 65536 * 6;  // 1179648
  constexpr int DL4 = 3 * 256 * 4;    // 3072
  constexpr int AL4 = 3 * 256 * 6;    // 4608
  constexpr int TOT = DP4 + AP4 + DL4 + AL4;  // 1973760
  int idx = blockIdx.x * 256 + threadIdx.x;
  int stride = gridDim.x * 256;
  for (; idx < TOT; idx += stride) {
    float4 v;
    if (idx < DP4) {
      int c4 = idx & 3; int hwi = idx >> 2; int hw = hwi & 65535; int i = hwi >> 16;
      const float* s = dp + (i * 16 + c4 * 4) * 65536 + hw;
      v.x = s[0]; v.y = s[65536]; v.z = s[131072]; v.w = s[196608];
    } else if (idx < DP4 + AP4) {
      int t = idx - DP4;
      int c4 = t % 6; int hwi = t / 6; int hw = hwi & 65535; int i = hwi >> 16;
      const float* s = ap + (i * 24 + c4 * 4) * 65536 + hw;
      v.x = s[0]; v.y = s[65536]; v.z = s[131072]; v.w = s[196608];
    } else if (idx < DP4 + AP4 + DL4) {
      int t = idx - (DP4 + AP4);
      int c4 = t & 3; int li = t >> 2; int l = li & 255; int i = li >> 8;
      const float* s = dl + (i * 16 + c4 * 4) * 256 + l;
      v.x = s[0]; v.y = s[256]; v.z = s[512]; v.w = s[768];
    } else {
      int t = idx - (DP4 + AP4 + DL4);
      int c4 = t % 6; int li = t / 6; int l = li & 255; int i = li >> 8;
      const float* s = al + (i * 24 + c4 * 4) * 256 + l;
      v.x = s[0]; v.y = s[256]; v.z = s[512]; v.w = s[768];
    }
    ws4[idx] = v;
  }
}

// ---------------------------------------------------------------------------
// Kernel A: per-sample gather+shade. 4 lanes per sample; lane `sub` owns
// channel-group sub (float4). One load instr = 16 samples x 64B contiguous.
// ---------------------------------------------------------------------------
__device__ __forceinline__ float density4(const float* __restrict__ plane,
                                          const float* __restrict__ line,
                                          float cx, float cy, float cw, int sub) {
  int x0, y0, l0; float wx, wy, wl;
  grid_uv(cx, x0, wx);
  grid_uv(cy, y0, wy);
  grid_uv(cw, l0, wl);
  const float* p = plane + (y0 * 256 + x0) * 16 + sub * 4;
  float4 v00 = ld4(p), v01 = ld4(p + 16), v10 = ld4(p + 4096), v11 = ld4(p + 4112);
  const float* lp = line + l0 * 16 + sub * 4;
  float4 la = ld4(lp), lb = ld4(lp + 16);
  float4 mid = lerp4(lerp4(v00, v01, wx), lerp4(v10, v11, wx), wy);
  float4 lv = lerp4(la, lb, wl);
  return dot4(mid, lv);
}

__device__ __forceinline__ void app4(const float* __restrict__ plane,
                                     const float* __restrict__ line,
                                     const float* __restrict__ btR,
                                     const float* __restrict__ btG,
                                     const float* __restrict__ btB,
                                     float cx, float cy, float cw, int sub,
                                     float& dr, float& dg, float& db) {
  int x0, y0, l0; float wx, wy, wl;
  grid_uv(cx, x0, wx);
  grid_uv(cy, y0, wy);
  grid_uv(cw, l0, wl);
  int base = (y0 * 256 + x0) * 24;
#pragma unroll
  for (int t = 0; t < 2; ++t) {
    int cc = sub + 4 * t;
    if (cc < 6) {
      const float* p = plane + base + cc * 4;
      float4 v00 = ld4(p), v01 = ld4(p + 24), v10 = ld4(p + 6144), v11 = ld4(p + 6168);
      const float* lp = line + l0 * 24 + cc * 4;
      float4 la = ld4(lp), lb = ld4(lp + 24);
      float4 mid = lerp4(lerp4(v00, v01, wx), lerp4(v10, v11, wx), wy);
      float4 lv = lerp4(la, lb, wl);
      float4 av;
      av.x = mid.x * lv.x; av.y = mid.y * lv.y;
      av.z = mid.z * lv.z; av.w = mid.w * lv.w;
      float4 br = ld4(btR + cc * 4);
      float4 bg = ld4(btG + cc * 4);
      float4 bb = ld4(btB + cc * 4);
      dr += dot4(av, br);
      dg += dot4(av, bg);
      db += dot4(av, bb);
    }
  }
}

__global__ __launch_bounds__(256) void sample_kernel(
    const float* __restrict__ rays, const float* __restrict__ basis,
    const float* __restrict__ aabb, const float* __restrict__ dpt,
    const float* __restrict__ dlt, const float* __restrict__ apt,
    const float* __restrict__ alt, float4* __restrict__ smp) {
  __shared__ __align__(16) float bt[3 * 72];  // bt[k][r] = basis[r][k]
  int tid = threadIdx.x;
  if (tid < 216) {
    int k = tid / 72, r = tid - k * 72;
    bt[tid] = basis[r * 3 + k];
  }
  __syncthreads();

  int g = (blockIdx.x * 256 + tid) >> 2;  // sample index
  int sub = tid & 3;                      // channel-group lane
  int ray = g >> 8, j = g & 255;

  float o0 = rays[ray * 6 + 0], o1 = rays[ray * 6 + 1], o2 = rays[ray * 6 + 2];
  float d0 = rays[ray * 6 + 3], d1 = rays[ray * 6 + 4], d2 = rays[ray * 6 + 5];
  float A0 = aabb[0], A1 = aabb[1], A2 = aabb[2];
  float B0 = aabb[3], B1 = aabb[4], B2 = aabb[5];

  float v0 = fabsf(d0) < 1e-6f ? 1e-6f : d0;
  float v1 = fabsf(d1) < 1e-6f ? 1e-6f : d1;
  float v2 = fabsf(d2) < 1e-6f ? 1e-6f : d2;
  float ra0 = (B0 - o0) / v0, rb0 = (A0 - o0) / v0;
  float ra1 = (B1 - o1) / v1, rb1 = (A1 - o1) / v1;
  float ra2 = (B2 - o2) / v2, rb2 = (A2 - o2) / v2;
  float tmin = fmaxf(fmaxf(fminf(ra0, rb0), fminf(ra1, rb1)), fminf(ra2, rb2));
  tmin = fmaxf(tmin, 0.05f);
  float tmax = fminf(fminf(fmaxf(ra0, rb0), fmaxf(ra1, rb1)), fmaxf(ra2, rb2));
  tmax = fmaxf(tmax, tmin + 0.001f);
  float dt = (tmax - tmin) * (1.0f / 255.0f);

  float s0 = 2.0f / (B0 - A0), s1 = 2.0f / (B1 - A1), s2 = 2.0f / (B2 - A2);
  float sfrac = (float)j * (1.0f / 255.0f);
  float z = tmin * (1.0f - sfrac) + tmax * sfrac;
  float c0 = (o0 + d0 * z - A0) * s0 - 1.0f;
  float c1 = (o1 + d1 * z - A1) * s1 - 1.0f;
  float c2 = (o2 + d2 * z - A2) * s2 - 1.0f;
  bool inside = (fabsf(c0) <= 1.0f) && (fabsf(c1) <= 1.0f) && (fabsf(c2) <= 1.0f);

  float sig = 0.f, dr = 0.f, dg = 0.f, db = 0.f;
  if (inside) {
    // MAT_MODE = [(0,1),(0,2),(1,2)], VEC_MODE = [2,1,0]
    sig += density4(dpt + 0 * 1048576, dlt + 0 * 4096, c0, c1, c2, sub);
    sig += density4(dpt + 1 * 1048576, dlt + 1 * 4096, c0, c2, c1, sub);
    sig += density4(dpt + 2 * 1048576, dlt + 2 * 4096, c1, c2, c0, sub);
    app4(apt + 0 * 1572864, alt + 0 * 6144,
         &bt[0 * 72 + 0], &bt[1 * 72 + 0], &bt[2 * 72 + 0],
         c0, c1, c2, sub, dr, dg, db);
    app4(apt + 1 * 1572864, alt + 1 * 6144,
         &bt[0 * 72 + 24], &bt[1 * 72 + 24], &bt[2 * 72 + 24],
         c0, c2, c1, sub, dr, dg, db);
    app4(apt + 2 * 1572864, alt + 2 * 6144,
         &bt[0 * 72 + 48], &bt[1 * 72 + 48], &bt[2 * 72 + 48],
         c1, c2, c0, sub, dr, dg, db);
  }
  // reduce over the 4-lane group
  sig += __shfl_xor(sig, 1, 64); sig += __shfl_xor(sig, 2, 64);
  dr  += __shfl_xor(dr, 1, 64);  dr  += __shfl_xor(dr, 2, 64);
  dg  += __shfl_xor(dg, 1, 64);  dg  += __shfl_xor(dg, 2, 64);
  db  += __shfl_xor(db, 1, 64);  db  += __shfl_xor(db, 2, 64);

  if (sub == 0) {
    float sp = fmaxf(sig, 0.f) + log1pf(expf(-fabsf(sig)));  // softplus
    float alpha = inside ? (1.0f - expf(-sp * dt)) : 0.0f;
    float4 outv;
    outv.x = alpha;
    outv.y = 1.0f / (1.0f + expf(-dr));
    outv.z = 1.0f / (1.0f + expf(-dg));
    outv.w = 1.0f / (1.0f + expf(-db));
    smp[g] = outv;
  }
}

// ---------------------------------------------------------------------------
// Kernel B: per-ray transmittance scan + composite. One wave per ray.
// ---------------------------------------------------------------------------
__global__ __launch_bounds__(256) void scan_kernel(
    const float* __restrict__ rays, const float* __restrict__ aabb,
    const float4* __restrict__ smp, float* __restrict__ out) {
  int tid = threadIdx.x;
  int lane = tid & 63;
  int ray = blockIdx.x * 4 + (tid >> 6);

  float o0 = rays[ray * 6 + 0], o1 = rays[ray * 6 + 1], o2 = rays[ray * 6 + 2];
  float d0 = rays[ray * 6 + 3], d1 = rays[ray * 6 + 4], d2 = rays[ray * 6 + 5];
  float A0 = aabb[0], A1 = aabb[1], A2 = aabb[2];
  float B0 = aabb[3], B1 = aabb[4], B2 = aabb[5];
  float v0 = fabsf(d0) < 1e-6f ? 1e-6f : d0;
  float v1 = fabsf(d1) < 1e-6f ? 1e-6f : d1;
  float v2 = fabsf(d2) < 1e-6f ? 1e-6f : d2;
  float ra0 = (B0 - o0) / v0, rb0 = (A0 - o0) / v0;
  float ra1 = (B1 - o1) / v1, rb1 = (A1 - o1) / v1;
  float ra2 = (B2 - o2) / v2, rb2 = (A2 - o2) / v2;
  float tmin = fmaxf(fmaxf(fminf(ra0, rb0), fminf(ra1, rb1)), fminf(ra2, rb2));
  tmin = fmaxf(tmin, 0.05f);
  float tmax = fminf(fminf(fmaxf(ra0, rb0), fmaxf(ra1, rb1)), fmaxf(ra2, rb2));
  tmax = fmaxf(tmax, tmin + 0.001f);

  float C = 1.0f;
  float racc = 0.f, gacc = 0.f, bacc = 0.f, wsum = 0.f, dsum = 0.f;

  for (int q = 0; q < 4; ++q) {
    int j = q * 64 + lane;
    float4 sv = smp[ray * 256 + j];
    float alpha = sv.x;
    float sfrac = (float)j * (1.0f / 255.0f);
    float z = tmin * (1.0f - sfrac) + tmax * sfrac;

    float p = 1.0f - alpha + 1e-10f;
#pragma unroll
    for (int off = 1; off < 64; off <<= 1) {
      float t = __shfl_up(p, off, 64);
      if (lane >= off) p *= t;
    }
    float tot = __shfl(p, 63, 64);
    float e = __shfl_up(p, 1, 64);
    if (lane == 0) e = 1.0f;
    float Tj = C * e;
    float w = alpha * Tj;
    racc += w * sv.y; gacc += w * sv.z; bacc += w * sv.w;
    wsum += w; dsum += w * z;
    C *= tot;
  }

#pragma unroll
  for (int off = 32; off > 0; off >>= 1) {
    racc += __shfl_down(racc, off, 64);
    gacc += __shfl_down(gacc, off, 64);
    bacc += __shfl_down(bacc, off, 64);
    wsum += __shfl_down(wsum, off, 64);
    dsum += __shfl_down(dsum, off, 64);
  }
  if (lane == 0) {
    float bgw = 1.0f - wsum;  // WHITE_BG
    out[ray * 3 + 0] = fminf(fmaxf(racc + bgw, 0.f), 1.f);
    out[ray * 3 + 1] = fminf(fmaxf(gacc + bgw, 0.f), 1.f);
    out[ray * 3 + 2] = fminf(fmaxf(bacc + bgw, 0.f), 1.f);
    out[NRAYS * 3 + ray] = dsum;
  }
}

// ---------------------------------------------------------------------------
// Fallback (ws too small): single-kernel render on original [c][y][x] layout.
// ---------------------------------------------------------------------------
__device__ __forceinline__ float density_orig(const float* __restrict__ plane,
                                              const float* __restrict__ line,
                                              float cx, float cy, float cw) {
  int x0, y0, l0; float wx, wy, wl;
  grid_uv(cx, x0, wx); grid_uv(cy, y0, wy); grid_uv(cw, l0, wl);
  int base = y0 * 256 + x0;
  float s = 0.0f;
#pragma unroll 4
  for (int c = 0; c < 16; ++c) {
    const float* pc = plane + c * 65536;
    float v00 = pc[base], v01 = pc[base + 1];
    float v10 = pc[base + 256], v11 = pc[base + 257];
    float top = fmaf(wx, v01 - v00, v00);
    float bot = fmaf(wx, v11 - v10, v10);
    float mid = fmaf(wy, bot - top, top);
    float la = line[c * 256 + l0], lb = line[c * 256 + l0 + 1];
    float lv = fmaf(wl, lb - la, la);
    s += mid * lv;
  }
  return s;
}

__device__ __forceinline__ void app_orig(const float* __restrict__ plane,
                                         const float* __restrict__ line,
                                         const float* __restrict__ btR,
                                         const float* __restrict__ btG,
                                         const float* __restrict__ btB,
                                         float cx, float cy, float cw,
                                         float& dr, float& dg, float& db) {
  int x0, y0, l0; float wx, wy, wl;
  grid_uv(cx, x0, wx); grid_uv(cy, y0, wy); grid_uv(cw, l0, wl);
  int base = y0 * 256 + x0;
#pragma unroll 4
  for (int c = 0; c < 24; ++c) {
    const float* pc = plane + c * 65536;
    float v00 = pc[base], v01 = pc[base + 1];
    float v10 = pc[base + 256], v11 = pc[base + 257];
    float top = fmaf(wx, v01 - v00, v00);
    float bot = fmaf(wx, v11 - v10, v10);
    float mid = fmaf(wy, bot - top, top);
    float la = line[c * 256 + l0], lb = line[c * 256 + l0 + 1];
    float lv = fmaf(wl, lb - la, la);
    float av = mid * lv;
    dr += av * btR[c]; dg += av * btG[c]; db += av * btB[c];
  }
}

__global__ __launch_bounds__(256) void render_fallback(
    const float* __restrict__ rays, const float* __restrict__ basis,
    const float* __restrict__ aabb, const float* __restrict__ dplane,
    const float* __restrict__ dline, const float* __restrict__ aplane,
    const float* __restrict__ aline, float* __restrict__ out) {
  __shared__ __align__(16) float bt[3 * 72];
  int tid = threadIdx.x;
  if (tid < 216) {
    int k = tid / 72, r = tid - k * 72;
    bt[tid] = basis[r * 3 + k];
  }
  __syncthreads();
  int lane = tid & 63;
  int ray = blockIdx.x * 4 + (tid >> 6);

  float o0 = rays[ray * 6 + 0], o1 = rays[ray * 6 + 1], o2 = rays[ray * 6 + 2];
  float d0 = rays[ray * 6 + 3], d1 = rays[ray * 6 + 4], d2 = rays[ray * 6 + 5];
  float A0 = aabb[0], A1 = aabb[1], A2 = aabb[2];
  float B0 = aabb[3], B1 = aabb[4], B2 = aabb[5];
  float v0 = fabsf(d0) < 1e-6f ? 1e-6f : d0;
  float v1 = fabsf(d1) < 1e-6f ? 1e-6f : d1;
  float v2 = fabsf(d2) < 1e-6f ? 1e-6f : d2;
  float ra0 = (B0 - o0) / v0, rb0 = (A0 - o0) / v0;
  float ra1 = (B1 - o1) / v1, rb1 = (A1 - o1) / v1;
  float ra2 = (B2 - o2) / v2, rb2 = (A2 - o2) / v2;
  float tmin = fmaxf(fmaxf(fminf(ra0, rb0), fminf(ra1, rb1)), fminf(ra2, rb2));
  tmin = fmaxf(tmin, 0.05f);
  float tmax = fminf(fminf(fmaxf(ra0, rb0), fmaxf(ra1, rb1)), fmaxf(ra2, rb2));
  tmax = fmaxf(tmax, tmin + 0.001f);
  float dt = (tmax - tmin) * (1.0f / 255.0f);
  float s0 = 2.0f / (B0 - A0), s1 = 2.0f / (B1 - A1), s2 = 2.0f / (B2 - A2);

  float C = 1.0f;
  float racc = 0.f, gacc = 0.f, bacc = 0.f, wsum = 0.f, dsum = 0.f;
  for (int q = 0; q < 4; ++q) {
    int j = q * 64 + lane;
    float sfrac = (float)j * (1.0f / 255.0f);
    float z = tmin * (1.0f - sfrac) + tmax * sfrac;
    float c0 = (o0 + d0 * z - A0) * s0 - 1.0f;
    float c1 = (o1 + d1 * z - A1) * s1 - 1.0f;
    float c2 = (o2 + d2 * z - A2) * s2 - 1.0f;
    bool inside = (fabsf(c0) <= 1.0f) && (fabsf(c1) <= 1.0f) && (fabsf(c2) <= 1.0f);
    float alpha = 0.f, cr = 0.f, cg = 0.f, cb = 0.f;
    if (inside) {
      float sig = 0.f, dr = 0.f, dg = 0.f, db = 0.f;
      sig += density_orig(dplane + 0 * 1048576, dline + 0 * 4096, c0, c1, c2);
      sig += density_orig(dplane + 1 * 1048576, dline + 1 * 4096, c0, c2, c1);
      sig += density_orig(dplane + 2 * 1048576, dline + 2 * 4096, c1, c2, c0);
      app_orig(aplane + 0 * 1572864, aline + 0 * 6144,
               &bt[0 * 72 + 0], &bt[1 * 72 + 0], &bt[2 * 72 + 0],
               c0, c1, c2, dr, dg, db);
      app_orig(aplane + 1 * 1572864, aline + 1 * 6144,
               &bt[0 * 72 + 24], &bt[1 * 72 + 24], &bt[2 * 72 + 24],
               c0, c2, c1, dr, dg, db);
      app_orig(aplane + 2 * 1572864, aline + 2 * 6144,
               &bt[0 * 72 + 48], &bt[1 * 72 + 48], &bt[2 * 72 + 48],
               c1, c2, c0, dr, dg, db);
      float sp = fmaxf(sig, 0.f) + log1pf(expf(-fabsf(sig)));
      alpha = 1.0f - expf(-sp * dt);
      cr = 1.0f / (1.0f + expf(-dr));
      cg = 1.0f / (1.0f + expf(-dg));
      cb = 1.0f / (1.0f + expf(-db));
    }
    float p = 1.0f - alpha + 1e-10f;
#pragma unroll
    for (int off = 1; off < 64; off <<= 1) {
      float t = __shfl_up(p, off, 64);
      if (lane >= off) p *= t;
    }
    float tot = __shfl(p, 63, 64);
    float e = __shfl_up(p, 1, 64);
    if (lane == 0) e = 1.0f;
    float Tj = C * e;
    float w = alpha * Tj;
    racc += w * cr; gacc += w * cg; bacc += w * cb;
    wsum += w; dsum += w * z;
    C *= tot;
  }
#pragma unroll
  for (int off = 32; off > 0; off >>= 1) {
    racc += __shfl_down(racc, off, 64);
    gacc += __shfl_down(gacc, off, 64);
    bacc += __shfl_down(bacc, off, 64);
    wsum += __shfl_down(wsum, off, 64);
    dsum += __shfl_down(dsum, off, 64);
  }
  if (lane == 0) {
    float bgw = 1.0f - wsum;
    out[ray * 3 + 0] = fminf(fmaxf(racc + bgw, 0.f), 1.f);
    out[ray * 3 + 1] = fminf(fmaxf(gacc + bgw, 0.f), 1.f);
    out[ray * 3 + 2] = fminf(fmaxf(bacc + bgw, 0.f), 1.f);
    out[NRAYS * 3 + ray] = dsum;
  }
}

extern "C" void kernel_launch(void* const* d_in, const int* in_sizes, int n_in,
                              void* d_out, int out_size, void* d_ws, size_t ws_size,
                              hipStream_t stream) {
  const float* rays  = (const float*)d_in[0];
  const float* dp    = (const float*)d_in[1];
  const float* dl    = (const float*)d_in[2];
  const float* ap    = (const float*)d_in[3];
  const float* al    = (const float*)d_in[4];
  const float* basis = (const float*)d_in[5];
  const float* aabb  = (const float*)d_in[6];
  float* out = (float*)d_out;

  if (ws_size >= WS_NEED_FULL) {
    float* ws = (float*)d_ws;
    float4* smp = (float4*)(ws + SMP_OFS);
    transpose4_kernel<<<7712, 256, 0, stream>>>(dp, dl, ap, al, (float4*)ws);
    sample_kernel<<<NSAMPLES_TOT * 4 / 256, 256, 0, stream>>>(
        rays, basis, aabb,
        ws, ws + DLT_OFS, ws + APT_OFS, ws + ALT_OFS, smp);
    scan_kernel<<<NRAYS / 4, 256, 0, stream>>>(rays, aabb, smp, out);
  } else {
    render_fallback<<<NRAYS / 4, 256, 0, stream>>>(
        rays, basis, aabb, dp, dl, ap, al, out);
  }
}